// Round 14
// baseline (142.353 us; speedup 1.0000x reference)
//
#include <hip/hip_runtime.h>

#define NN 100000
#define NE 1200000
#define NPOS 100000
#define NNEG 100000

#define NBUCK ((NN + 255) / 256)    // 391 buckets of 256 nodes
#define BCAP 3712                   // mean 3070, sd ~55 -> 11.7 sigma margin
#define TILE 2048
#define EPT 4                       // edges per thread in bin_kernel (512 threads)

typedef unsigned short bf16_t;

__device__ __forceinline__ float bf2f(bf16_t b) {
    return __uint_as_float(((unsigned int)b) << 16);
}
__device__ __forceinline__ bf16_t f2bf(float f) {
    unsigned int u = __float_as_uint(f);
    u += 0x7FFFu + ((u >> 16) & 1u);  // round-to-nearest-even
    return (bf16_t)(u >> 16);
}
__device__ __forceinline__ float ulo(unsigned int u) { return bf2f((bf16_t)(u & 0xFFFFu)); }
__device__ __forceinline__ float uhi(unsigned int u) { return bf2f((bf16_t)(u >> 16)); }

__device__ __forceinline__ void acc8(float* a, uint4 u) {
    a[0] += ulo(u.x); a[1] += uhi(u.x);
    a[2] += ulo(u.y); a[3] += uhi(u.y);
    a[4] += ulo(u.z); a[5] += uhi(u.z);
    a[6] += ulo(u.w); a[7] += uhi(u.w);
}

#define GETC(v, i) ((i) == 0 ? (v).x : (i) == 1 ? (v).y : (i) == 2 ? (v).z : (v).w)

// ---------------- tiny zero kernel ----------------

__global__ __launch_bounds__(256) void zero_gcur_kernel(int* __restrict__ gcur) {
    int i = blockIdx.x * 256 + threadIdx.x;
    if (i < NBUCK) gcur[i] = 0;
}

// ---------------- stage 1: bin edges by dst bucket (dst>>8) ----------------

__global__ __launch_bounds__(512) void bin_kernel(const int* __restrict__ src,
                                                  const int* __restrict__ dst,
                                                  int* __restrict__ gcur,
                                                  unsigned int* __restrict__ brec) {
    __shared__ int hcnt[NBUCK];
    __shared__ int hbase[NBUCK];
    for (int b = threadIdx.x; b < NBUCK; b += 512) hcnt[b] = 0;
    __syncthreads();

    const int tile0 = blockIdx.x * TILE;
    int bk[EPT];
    int rank[EPT];
    unsigned int rec[EPT];
#pragma unroll
    for (int i = 0; i < EPT; ++i) {
        int e = tile0 + i * 512 + threadIdx.x;
        if (e < NE) {
            int s = src[e];
            int d = dst[e];
            bk[i] = d >> 8;
            rec[i] = ((unsigned int)(d & 255) << 24) | (unsigned int)s;
            rank[i] = atomicAdd(&hcnt[bk[i]], 1);
        } else {
            bk[i] = -1;
        }
    }
    __syncthreads();
    for (int b = threadIdx.x; b < NBUCK; b += 512) {
        int h = hcnt[b];
        if (h > 0) hbase[b] = atomicAdd(&gcur[b], h);
    }
    __syncthreads();
#pragma unroll
    for (int i = 0; i < EPT; ++i) {
        if (bk[i] >= 0) {
            int p = hbase[bk[i]] + rank[i];
            if (p < BCAP) brec[(size_t)bk[i] * BCAP + p] = rec[i];
        }
    }
}

// ---------------- stage 2: per-bucket sort by dstLocal -> CSR slice + degree-ordered perm ----------------

__global__ __launch_bounds__(256) void bucket_csr_kernel(const int* __restrict__ gcur,
                                                         const unsigned int* __restrict__ brec,
                                                         int* __restrict__ csr,
                                                         int* __restrict__ st,
                                                         int* __restrict__ en,
                                                         float* __restrict__ dis,
                                                         int* __restrict__ ord) {
    __shared__ int hist[256];
    __shared__ int scanv[256];
    __shared__ int cur[256];
    __shared__ int sorted[BCAP];
    __shared__ int dhist[64];
    __shared__ int dscan[64];
    __shared__ int dcur[64];
    const int b = blockIdx.x;
    const int t = threadIdx.x;
    const int n = min(gcur[b], BCAP);
    const unsigned int* rec = brec + (size_t)b * BCAP;

    hist[t] = 0;
    if (t < 64) dhist[t] = 0;
    __syncthreads();
    for (int i = t; i < n; i += 256) atomicAdd(&hist[rec[i] >> 24], 1);
    __syncthreads();

    int c = hist[t];
    scanv[t] = c;
    __syncthreads();
    for (int off = 1; off < 256; off <<= 1) {
        int add = (t >= off) ? scanv[t - off] : 0;
        __syncthreads();
        scanv[t] += add;
        __syncthreads();
    }
    int base = scanv[t] - c;  // exclusive
    cur[t] = base;
    __syncthreads();

    for (int i = t; i < n; i += 256) {
        unsigned int r = rec[i];
        int p = atomicAdd(&cur[r >> 24], 1);
        sorted[p] = (int)(r & 0xFFFFFF);
    }
    __syncthreads();

    for (int i = t; i < n; i += 256) csr[(size_t)b * BCAP + i] = sorted[i];

    const int v = b * 256 + t;
    const bool valid = v < NN;
    const int key = min(c, 63);
    if (valid) {
        st[v] = b * BCAP + base;
        en[v] = b * BCAP + base + c;
        dis[v] = rsqrtf((float)(c + 1));
        atomicAdd(&dhist[key], 1);
    }
    __syncthreads();

    // exclusive scan over 64 degree bins
    if (t < 64) dscan[t] = dhist[t];
    __syncthreads();
    for (int off = 1; off < 64; off <<= 1) {
        int add = (t < 64 && t >= off) ? dscan[t - off] : 0;
        __syncthreads();
        if (t < 64) dscan[t] += add;
        __syncthreads();
    }
    if (t < 64) dcur[t] = dscan[t] - dhist[t];
    __syncthreads();

    if (valid) {
        int p = atomicAdd(&dcur[key], 1);
        ord[b * 256 + p] = v;     // dense: bucket b occupies [b*256, b*256 + #valid)
    }
}

// ---------------- tiled GEMM core (64 rows, padded-17 float4 LDS) ----------------

__device__ __forceinline__ void gemm_tile_compute(const float4* __restrict__ xs4,
                                                  const float4* __restrict__ ws4,
                                                  int ty, int tx, float acc[4][4]) {
#pragma unroll 2
    for (int k4 = 0; k4 < 16; ++k4) {
        float4 xa0 = xs4[(ty * 4 + 0) * 17 + k4];
        float4 xa1 = xs4[(ty * 4 + 1) * 17 + k4];
        float4 xa2 = xs4[(ty * 4 + 2) * 17 + k4];
        float4 xa3 = xs4[(ty * 4 + 3) * 17 + k4];
        float4 wk0 = ws4[(k4 * 4 + 0) * 16 + tx];
        float4 wk1 = ws4[(k4 * 4 + 1) * 16 + tx];
        float4 wk2 = ws4[(k4 * 4 + 2) * 16 + tx];
        float4 wk3 = ws4[(k4 * 4 + 3) * 16 + tx];
#pragma unroll
        for (int kk = 0; kk < 4; ++kk) {
            float4 wv = (kk == 0) ? wk0 : (kk == 1) ? wk1 : (kk == 2) ? wk2 : wk3;
            float x0 = GETC(xa0, kk), x1 = GETC(xa1, kk);
            float x2 = GETC(xa2, kk), x3 = GETC(xa3, kk);
            acc[0][0] += x0 * wv.x; acc[0][1] += x0 * wv.y; acc[0][2] += x0 * wv.z; acc[0][3] += x0 * wv.w;
            acc[1][0] += x1 * wv.x; acc[1][1] += x1 * wv.y; acc[1][2] += x1 * wv.z; acc[1][3] += x1 * wv.w;
            acc[2][0] += x2 * wv.x; acc[2][1] += x2 * wv.y; acc[2][2] += x2 * wv.z; acc[2][3] += x2 * wv.w;
            acc[3][0] += x3 * wv.x; acc[3][1] += x3 * wv.y; acc[3][2] += x3 * wv.z; acc[3][3] += x3 * wv.w;
        }
    }
}

// ---------------- layer-1 transform: H' = (X @ W) * dis[row]  (f32 in, bf16 out) ----------------

__global__ __launch_bounds__(256) void gemm64_f32in_kernel(const float* __restrict__ X,
                                                           const float* __restrict__ W,
                                                           const float* __restrict__ dis,
                                                           bf16_t* __restrict__ Hout, int n) {
    __shared__ float4 xs4[64 * 17];   // padded rows
    __shared__ float4 ws4[64 * 16];
    const int tx = threadIdx.x & 15;
    const int ty = threadIdx.x >> 4;
    const int row0 = blockIdx.x * 64;

    const float4* X4 = reinterpret_cast<const float4*>(X + (size_t)row0 * 64);
    const float4* W4 = reinterpret_cast<const float4*>(W);

#pragma unroll
    for (int i = 0; i < 4; ++i) {
        int idx = threadIdx.x + i * 256;       // float4 index, 1024 total
        int r = idx >> 4, c4 = idx & 15;
        int row = row0 + r;
        xs4[r * 17 + c4] = (row < n) ? X4[idx] : make_float4(0.f, 0.f, 0.f, 0.f);
        ws4[idx] = W4[idx];
    }
    __syncthreads();

    float acc[4][4] = {};
    gemm_tile_compute(xs4, ws4, ty, tx, acc);

#pragma unroll
    for (int r = 0; r < 4; ++r) {
        int rw = row0 + ty * 4 + r;
        if (rw < n) {
            float d = dis[rw];
            unsigned int lo = (unsigned int)f2bf(acc[r][0] * d) |
                              ((unsigned int)f2bf(acc[r][1] * d) << 16);
            unsigned int hi = (unsigned int)f2bf(acc[r][2] * d) |
                              ((unsigned int)f2bf(acc[r][3] * d) << 16);
            uint2 u; u.x = lo; u.y = hi;
            *reinterpret_cast<uint2*>(&Hout[(size_t)rw * 64 + tx * 4]) = u;
        }
    }
}

// ---------------- FUSED: agg layer-1 + relu + gemm W2 + dis-scale (degree-ordered) ----------------

__global__ __launch_bounds__(256) void agg_gemm_kernel(const int* __restrict__ csr,
                                                       const int* __restrict__ st,
                                                       const int* __restrict__ en,
                                                       const float* __restrict__ dis,
                                                       const uint4* __restrict__ Hp8,
                                                       const float* __restrict__ bias,
                                                       const float* __restrict__ W2,
                                                       const int* __restrict__ ord,
                                                       bf16_t* __restrict__ Hout, int n) {
    __shared__ float4 zs4[32 * 17];   // relu(z1), padded rows
    __shared__ float4 ws4[64 * 16];   // W2
    __shared__ int vmap[32];
    const int lane = threadIdx.x & 63;
    const int g = lane >> 3;
    const int fl = lane & 7;
    const int i0 = blockIdx.x * 32;
    const int lrow = ((threadIdx.x >> 6) << 3) + g;   // local row 0..31
    const int idx = i0 + lrow;
    const bool act = idx < n;
    const int v = ord[act ? idx : (n - 1)];
    if (fl == 0) vmap[lrow] = act ? v : -1;

    // cooperative W2 load (independent of gather)
    const float4* W4 = reinterpret_cast<const float4*>(W2);
#pragma unroll
    for (int i = 0; i < 4; ++i) ws4[threadIdx.x + i * 256] = W4[threadIdx.x + i * 256];

    // ---- phase 1: gather ----
    int e = st[v];
    const int e1 = en[v];
    float a0[8] = {}, a1[8] = {}, a2[8] = {}, a3[8] = {};
    acc8(a0, Hp8[(size_t)v * 8 + fl]);   // self loop

    for (; e + 4 <= e1; e += 4) {
        int s0 = csr[e];
        int s1 = csr[e + 1];
        int s2 = csr[e + 2];
        int s3 = csr[e + 3];
        uint4 u0 = Hp8[(size_t)s0 * 8 + fl];
        uint4 u1 = Hp8[(size_t)s1 * 8 + fl];
        uint4 u2 = Hp8[(size_t)s2 * 8 + fl];
        uint4 u3 = Hp8[(size_t)s3 * 8 + fl];
        acc8(a0, u0);
        acc8(a1, u1);
        acc8(a2, u2);
        acc8(a3, u3);
    }
    for (; e < e1; ++e) acc8(a1, Hp8[(size_t)csr[e] * 8 + fl]);

    {
        float d = dis[v];
        float4 bA = reinterpret_cast<const float4*>(bias)[fl * 2];
        float4 bB = reinterpret_cast<const float4*>(bias)[fl * 2 + 1];
        float4 zA, zB;
        zA.x = fmaxf(((a0[0] + a1[0]) + (a2[0] + a3[0])) * d + bA.x, 0.f);
        zA.y = fmaxf(((a0[1] + a1[1]) + (a2[1] + a3[1])) * d + bA.y, 0.f);
        zA.z = fmaxf(((a0[2] + a1[2]) + (a2[2] + a3[2])) * d + bA.z, 0.f);
        zA.w = fmaxf(((a0[3] + a1[3]) + (a2[3] + a3[3])) * d + bA.w, 0.f);
        zB.x = fmaxf(((a0[4] + a1[4]) + (a2[4] + a3[4])) * d + bB.x, 0.f);
        zB.y = fmaxf(((a0[5] + a1[5]) + (a2[5] + a3[5])) * d + bB.y, 0.f);
        zB.z = fmaxf(((a0[6] + a1[6]) + (a2[6] + a3[6])) * d + bB.z, 0.f);
        zB.w = fmaxf(((a0[7] + a1[7]) + (a2[7] + a3[7])) * d + bB.w, 0.f);
        zs4[lrow * 17 + fl * 2]     = zA;
        zs4[lrow * 17 + fl * 2 + 1] = zB;
    }
    __syncthreads();

    // ---- phase 2: 32-row tile gemm, thread owns 2 rows x 4 cols ----
    const int tx = threadIdx.x & 15;
    const int ty = threadIdx.x >> 4;
    float acc[2][4] = {};
#pragma unroll 2
    for (int k4 = 0; k4 < 16; ++k4) {
        float4 xa0 = zs4[(ty * 2 + 0) * 17 + k4];
        float4 xa1 = zs4[(ty * 2 + 1) * 17 + k4];
        float4 wk0 = ws4[(k4 * 4 + 0) * 16 + tx];
        float4 wk1 = ws4[(k4 * 4 + 1) * 16 + tx];
        float4 wk2 = ws4[(k4 * 4 + 2) * 16 + tx];
        float4 wk3 = ws4[(k4 * 4 + 3) * 16 + tx];
#pragma unroll
        for (int kk = 0; kk < 4; ++kk) {
            float4 wv = (kk == 0) ? wk0 : (kk == 1) ? wk1 : (kk == 2) ? wk2 : wk3;
            float x0 = GETC(xa0, kk), x1 = GETC(xa1, kk);
            acc[0][0] += x0 * wv.x; acc[0][1] += x0 * wv.y; acc[0][2] += x0 * wv.z; acc[0][3] += x0 * wv.w;
            acc[1][0] += x1 * wv.x; acc[1][1] += x1 * wv.y; acc[1][2] += x1 * wv.z; acc[1][3] += x1 * wv.w;
        }
    }
#pragma unroll
    for (int r = 0; r < 2; ++r) {
        int rw = vmap[ty * 2 + r];
        if (rw >= 0) {
            float d = dis[rw];
            unsigned int lo = (unsigned int)f2bf(acc[r][0] * d) |
                              ((unsigned int)f2bf(acc[r][1] * d) << 16);
            unsigned int hi = (unsigned int)f2bf(acc[r][2] * d) |
                              ((unsigned int)f2bf(acc[r][3] * d) << 16);
            uint2 u; u.x = lo; u.y = hi;
            *reinterpret_cast<uint2*>(&Hout[(size_t)rw * 64 + tx * 4]) = u;
        }
    }
}

// ---------------- gather aggregation (layer 2): 8-lane group per node, degree-ordered ----------------

__global__ __launch_bounds__(256) void agg_kernel(const int* __restrict__ csr,
                                                  const int* __restrict__ st,
                                                  const int* __restrict__ en,
                                                  const float* __restrict__ dis,
                                                  const uint4* __restrict__ Hp8,
                                                  const float* __restrict__ bias,
                                                  const int* __restrict__ ord,
                                                  uint4* __restrict__ Z8, int n) {
    const int lane = threadIdx.x & 63;
    const int g = lane >> 3;        // group 0..7
    const int fl = lane & 7;        // feature-lane
    const int idx = blockIdx.x * 32 + ((threadIdx.x >> 6) << 3) + g;
    const bool act = idx < n;
    const int v = ord[act ? idx : (n - 1)];

    int e = st[v];
    const int e1 = en[v];

    float a0[8] = {}, a1[8] = {}, a2[8] = {}, a3[8] = {};
    acc8(a0, Hp8[(size_t)v * 8 + fl]);   // self loop seeds chain 0

    for (; e + 4 <= e1; e += 4) {
        int s0 = csr[e];
        int s1 = csr[e + 1];
        int s2 = csr[e + 2];
        int s3 = csr[e + 3];
        uint4 u0 = Hp8[(size_t)s0 * 8 + fl];
        uint4 u1 = Hp8[(size_t)s1 * 8 + fl];
        uint4 u2 = Hp8[(size_t)s2 * 8 + fl];
        uint4 u3 = Hp8[(size_t)s3 * 8 + fl];
        acc8(a0, u0);
        acc8(a1, u1);
        acc8(a2, u2);
        acc8(a3, u3);
    }
    for (; e < e1; ++e) {
        acc8(a1, Hp8[(size_t)csr[e] * 8 + fl]);
    }

    if (act) {
        float d = dis[v];
        float4 bA = reinterpret_cast<const float4*>(bias)[fl * 2];
        float4 bB = reinterpret_cast<const float4*>(bias)[fl * 2 + 1];
        float z0 = ((a0[0] + a1[0]) + (a2[0] + a3[0])) * d + bA.x;
        float z1 = ((a0[1] + a1[1]) + (a2[1] + a3[1])) * d + bA.y;
        float z2 = ((a0[2] + a1[2]) + (a2[2] + a3[2])) * d + bA.z;
        float z3 = ((a0[3] + a1[3]) + (a2[3] + a3[3])) * d + bA.w;
        float z4 = ((a0[4] + a1[4]) + (a2[4] + a3[4])) * d + bB.x;
        float z5 = ((a0[5] + a1[5]) + (a2[5] + a3[5])) * d + bB.y;
        float z6 = ((a0[6] + a1[6]) + (a2[6] + a3[6])) * d + bB.z;
        float z7 = ((a0[7] + a1[7]) + (a2[7] + a3[7])) * d + bB.w;
        uint4 u;
        u.x = (unsigned int)f2bf(z0) | ((unsigned int)f2bf(z1) << 16);
        u.y = (unsigned int)f2bf(z2) | ((unsigned int)f2bf(z3) << 16);
        u.z = (unsigned int)f2bf(z4) | ((unsigned int)f2bf(z5) << 16);
        u.w = (unsigned int)f2bf(z6) | ((unsigned int)f2bf(z7) << 16);
        Z8[(size_t)v * 8 + fl] = u;
    }
}

// ---------------- decoder: 8-lane group per pair, uint4 lanes ----------------

__global__ __launch_bounds__(256) void decode_kernel(const int* __restrict__ pos,
                                                     const int* __restrict__ neg,
                                                     const uint4* __restrict__ Z8,
                                                     float* __restrict__ out) {
    const int lane = threadIdx.x & 63;
    const int fl = lane & 7;
    const int pair = blockIdx.x * 32 + ((threadIdx.x >> 6) << 3) + (lane >> 3);
    if (pair >= NPOS + NNEG) return;
    int a, b;
    if (pair < NPOS) {
        a = pos[pair];
        b = pos[NPOS + pair];
    } else {
        int p = pair - NPOS;
        a = neg[p];
        b = neg[NNEG + p];
    }
    uint4 ua = Z8[(size_t)a * 8 + fl];
    uint4 ub = Z8[(size_t)b * 8 + fl];
    float v = ulo(ua.x) * ulo(ub.x) + uhi(ua.x) * uhi(ub.x)
            + ulo(ua.y) * ulo(ub.y) + uhi(ua.y) * uhi(ub.y)
            + ulo(ua.z) * ulo(ub.z) + uhi(ua.z) * uhi(ub.z)
            + ulo(ua.w) * ulo(ub.w) + uhi(ua.w) * uhi(ub.w);
#pragma unroll
    for (int off = 4; off > 0; off >>= 1) v += __shfl_xor(v, off, 64);
    if (fl == 0) out[pair] = v;
}

// ---------------- fallback (round-0 atomic path, all f32) ----------------

__global__ __launch_bounds__(256) void init_deg_kernel(float* __restrict__ deg, int n) {
    int i = blockIdx.x * 256 + threadIdx.x;
    if (i < n) deg[i] = 1.0f;
}
__global__ __launch_bounds__(256) void deg_count_kernel(const int* __restrict__ dst,
                                                        float* __restrict__ deg, int e) {
    int i = blockIdx.x * 256 + threadIdx.x;
    if (i < e) atomicAdd(&deg[dst[i]], 1.0f);
}
__global__ __launch_bounds__(256) void dis_kernel(float* __restrict__ deg, int n) {
    int i = blockIdx.x * 256 + threadIdx.x;
    if (i < n) deg[i] = rsqrtf(deg[i]);
}
template <bool RELU>
__global__ __launch_bounds__(256) void gemm64_f32out_kernel(const float* __restrict__ X,
                                                            const float* __restrict__ W,
                                                            float* __restrict__ Hout, int n) {
    __shared__ float xs[64][64];
    const int lane = threadIdx.x & 63;
    const int wid = threadIdx.x >> 6;
    float w[64];
#pragma unroll
    for (int k = 0; k < 64; ++k) w[k] = W[k * 64 + lane];
    const int row0 = blockIdx.x * 64;
#pragma unroll
    for (int i = 0; i < 16; ++i) {
        int idx = threadIdx.x + i * 256;
        int r = idx >> 6, c = idx & 63;
        int row = row0 + r;
        float v = (row < n) ? X[(size_t)row * 64 + c] : 0.0f;
        if (RELU) v = fmaxf(v, 0.0f);
        xs[r][c] = v;
    }
    __syncthreads();
#pragma unroll 1
    for (int rr = 0; rr < 16; ++rr) {
        int r = wid * 16 + rr;
        int row = row0 + r;
        if (row < n) {
            float acc = 0.0f;
#pragma unroll
            for (int k = 0; k < 64; ++k) acc += xs[r][k] * w[k];
            Hout[(size_t)row * 64 + lane] = acc;
        }
    }
}
__global__ __launch_bounds__(256) void selfloop_init_kernel(const float* __restrict__ H,
                                                            const float* __restrict__ dis,
                                                            const float* __restrict__ b,
                                                            float* __restrict__ Z, int n) {
    int i = blockIdx.x * 256 + threadIdx.x;
    if (i < n * 16) {
        int v = i >> 4, c = i & 15;
        float d = dis[v], d2 = d * d;
        float4 h4 = reinterpret_cast<const float4*>(H)[i];
        float4 b4 = reinterpret_cast<const float4*>(b)[c];
        float4 z4;
        z4.x = b4.x + h4.x * d2;
        z4.y = b4.y + h4.y * d2;
        z4.z = b4.z + h4.z * d2;
        z4.w = b4.w + h4.w * d2;
        reinterpret_cast<float4*>(Z)[i] = z4;
    }
}
__global__ __launch_bounds__(256) void edge_agg_kernel(const int* __restrict__ src,
                                                       const int* __restrict__ dst,
                                                       const float* __restrict__ dis,
                                                       const float* __restrict__ H,
                                                       float* __restrict__ Z, int e) {
    const int lane = threadIdx.x & 63;
    const int edge = blockIdx.x * 4 + (threadIdx.x >> 6);
    if (edge < e) {
        int s = src[edge];
        int d = dst[edge];
        float nm = dis[s] * dis[d];
        float v = H[(size_t)s * 64 + lane] * nm;
        atomicAdd(&Z[(size_t)d * 64 + lane], v);
    }
}
__global__ __launch_bounds__(256) void decode_f32_kernel(const int* __restrict__ pos,
                                                         const int* __restrict__ neg,
                                                         const float* __restrict__ Z,
                                                         float* __restrict__ out) {
    const int lane = threadIdx.x & 63;
    const int pair = blockIdx.x * 4 + (threadIdx.x >> 6);
    if (pair >= NPOS + NNEG) return;
    int a, b;
    if (pair < NPOS) {
        a = pos[pair];
        b = pos[NPOS + pair];
    } else {
        int p = pair - NPOS;
        a = neg[p];
        b = neg[NNEG + p];
    }
    float v = Z[(size_t)a * 64 + lane] * Z[(size_t)b * 64 + lane];
#pragma unroll
    for (int off = 32; off > 0; off >>= 1) v += __shfl_down(v, off, 64);
    if (lane == 0) out[pair] = v;
}

// ---------------- launch ----------------

extern "C" void kernel_launch(void* const* d_in, const int* in_sizes, int n_in,
                              void* d_out, int out_size, void* d_ws, size_t ws_size,
                              hipStream_t stream) {
    const float* x   = (const float*)d_in[0];
    const int*   ei  = (const int*)d_in[1];
    const int*   pos = (const int*)d_in[2];
    const int*   neg = (const int*)d_in[3];
    const float* W1  = (const float*)d_in[4];
    const float* b1  = (const float*)d_in[5];
    const float* W2  = (const float*)d_in[6];
    const float* b2  = (const float*)d_in[7];
    float* out = (float*)d_out;

    const int* src = ei;
    const int* dst = ei + NE;

    char* ws = (char*)d_ws;
    size_t o = 0;
    auto alloc = [&](size_t bytes) {
        size_t p = o;
        o = (o + bytes + 255) & ~(size_t)255;
        return p;
    };
    float*        dis  = (float*)(ws + alloc((size_t)NN * 4));
    int*          gcur = (int*)(ws + alloc((size_t)NBUCK * 4));
    unsigned int* brec = (unsigned int*)(ws + alloc((size_t)NBUCK * BCAP * 4));
    int*          csr  = (int*)(ws + alloc((size_t)NBUCK * BCAP * 4));
    int*          stA  = (int*)(ws + alloc((size_t)NN * 4));
    int*          enA  = (int*)(ws + alloc((size_t)NN * 4));
    int*          ord  = (int*)(ws + alloc((size_t)NN * 4));
    bf16_t*       bufA = (bf16_t*)(ws + alloc((size_t)NN * 64 * 2));
    bf16_t*       bufB = (bf16_t*)(ws + alloc((size_t)NN * 64 * 2));

    if (o <= ws_size) {
        // ---- bucketed CSR gather path (bf16, degree-ordered agg, fused agg1+gemm2) ----
        zero_gcur_kernel<<<(NBUCK + 255) / 256, 256, 0, stream>>>(gcur);
        bin_kernel<<<(NE + TILE - 1) / TILE, 512, 0, stream>>>(src, dst, gcur, brec);
        bucket_csr_kernel<<<NBUCK, 256, 0, stream>>>(gcur, brec, csr, stA, enA, dis, ord);

        gemm64_f32in_kernel<<<(NN + 63) / 64, 256, 0, stream>>>(x, W1, dis, bufA, NN);

        // fused: agg layer1 (reads bufA) + relu + @W2 + dis -> bufB (= H2')
        agg_gemm_kernel<<<(NN + 31) / 32, 256, 0, stream>>>(csr, stA, enA, dis,
                                                            (const uint4*)bufA, b1, W2,
                                                            ord, bufB, NN);

        // agg layer2 -> bufA (= z2)
        agg_kernel<<<(NN + 31) / 32, 256, 0, stream>>>(csr, stA, enA, dis,
                                                       (const uint4*)bufB, b2,
                                                       ord, (uint4*)bufA, NN);

        decode_kernel<<<((NPOS + NNEG) + 31) / 32, 256, 0, stream>>>(pos, neg,
                                                                     (const uint4*)bufA, out);
    } else {
        // ---- fallback: atomic scatter path (f32) ----
        float* fdis = (float*)ws;
        size_t foff = ((size_t)NN * 4 + 255) / 256 * 256;
        float* fA = (float*)(ws + foff);
        float* fB = fA + (size_t)NN * 64;

        init_deg_kernel<<<(NN + 255) / 256, 256, 0, stream>>>(fdis, NN);
        deg_count_kernel<<<(NE + 255) / 256, 256, 0, stream>>>(dst, fdis, NE);
        dis_kernel<<<(NN + 255) / 256, 256, 0, stream>>>(fdis, NN);

        gemm64_f32out_kernel<false><<<(NN + 63) / 64, 256, 0, stream>>>(x, W1, fA, NN);
        selfloop_init_kernel<<<(NN * 16 + 255) / 256, 256, 0, stream>>>(fA, fdis, b1, fB, NN);
        edge_agg_kernel<<<(NE + 3) / 4, 256, 0, stream>>>(src, dst, fdis, fA, fB, NE);

        gemm64_f32out_kernel<true><<<(NN + 63) / 64, 256, 0, stream>>>(fB, W2, fA, NN);
        selfloop_init_kernel<<<(NN * 16 + 255) / 256, 256, 0, stream>>>(fA, fdis, b2, fB, NN);
        edge_agg_kernel<<<(NE + 3) / 4, 256, 0, stream>>>(src, dst, fdis, fA, fB, NE);

        decode_f32_kernel<<<((NPOS + NNEG) + 3) / 4, 256, 0, stream>>>(pos, neg, fB, out);
    }
}

// Round 15
// 129.421 us; speedup vs baseline: 1.0999x; 1.0999x over previous
//
#include <hip/hip_runtime.h>

#define NN 100000
#define NE 1200000
#define NPOS 100000
#define NNEG 100000

#define NBUCK ((NN + 255) / 256)    // 391 buckets of 256 nodes
#define BCAP 3712                   // mean 3070, sd ~55 -> 11.7 sigma margin
#define TILE 2048
#define EPT 4                       // edges per thread in bin_kernel (512 threads)

typedef unsigned short bf16_t;

__device__ __forceinline__ float bf2f(bf16_t b) {
    return __uint_as_float(((unsigned int)b) << 16);
}
__device__ __forceinline__ bf16_t f2bf(float f) {
    unsigned int u = __float_as_uint(f);
    u += 0x7FFFu + ((u >> 16) & 1u);  // round-to-nearest-even
    return (bf16_t)(u >> 16);
}
__device__ __forceinline__ float ulo(unsigned int u) { return bf2f((bf16_t)(u & 0xFFFFu)); }
__device__ __forceinline__ float uhi(unsigned int u) { return bf2f((bf16_t)(u >> 16)); }

__device__ __forceinline__ void acc8(float* a, uint4 u) {
    a[0] += ulo(u.x); a[1] += uhi(u.x);
    a[2] += ulo(u.y); a[3] += uhi(u.y);
    a[4] += ulo(u.z); a[5] += uhi(u.z);
    a[6] += ulo(u.w); a[7] += uhi(u.w);
}

#define GETC(v, i) ((i) == 0 ? (v).x : (i) == 1 ? (v).y : (i) == 2 ? (v).z : (v).w)

// ---------------- tiny zero kernel ----------------

__global__ __launch_bounds__(256) void zero_gcur_kernel(int* __restrict__ gcur) {
    int i = blockIdx.x * 256 + threadIdx.x;
    if (i < NBUCK) gcur[i] = 0;
}

// ---------------- stage 1: bin edges by dst bucket (dst>>8) ----------------

__global__ __launch_bounds__(512) void bin_kernel(const int* __restrict__ src,
                                                  const int* __restrict__ dst,
                                                  int* __restrict__ gcur,
                                                  unsigned int* __restrict__ brec) {
    __shared__ int hcnt[NBUCK];
    __shared__ int hbase[NBUCK];
    for (int b = threadIdx.x; b < NBUCK; b += 512) hcnt[b] = 0;
    __syncthreads();

    const int tile0 = blockIdx.x * TILE;
    int bk[EPT];
    int rank[EPT];
    unsigned int rec[EPT];
#pragma unroll
    for (int i = 0; i < EPT; ++i) {
        int e = tile0 + i * 512 + threadIdx.x;
        if (e < NE) {
            int s = src[e];
            int d = dst[e];
            bk[i] = d >> 8;
            rec[i] = ((unsigned int)(d & 255) << 24) | (unsigned int)s;
            rank[i] = atomicAdd(&hcnt[bk[i]], 1);
        } else {
            bk[i] = -1;
        }
    }
    __syncthreads();
    for (int b = threadIdx.x; b < NBUCK; b += 512) {
        int h = hcnt[b];
        if (h > 0) hbase[b] = atomicAdd(&gcur[b], h);
    }
    __syncthreads();
#pragma unroll
    for (int i = 0; i < EPT; ++i) {
        if (bk[i] >= 0) {
            int p = hbase[bk[i]] + rank[i];
            if (p < BCAP) brec[(size_t)bk[i] * BCAP + p] = rec[i];
        }
    }
}

// ---------------- stage 2: per-bucket sort by dstLocal -> CSR slice ----------------

__global__ __launch_bounds__(256) void bucket_csr_kernel(const int* __restrict__ gcur,
                                                         const unsigned int* __restrict__ brec,
                                                         int* __restrict__ csr,
                                                         int* __restrict__ st,
                                                         int* __restrict__ en,
                                                         float* __restrict__ dis) {
    __shared__ int hist[256];
    __shared__ int scanv[256];
    __shared__ int cur[256];
    __shared__ int sorted[BCAP];
    const int b = blockIdx.x;
    const int t = threadIdx.x;
    const int n = min(gcur[b], BCAP);
    const unsigned int* rec = brec + (size_t)b * BCAP;

    hist[t] = 0;
    __syncthreads();
    for (int i = t; i < n; i += 256) atomicAdd(&hist[rec[i] >> 24], 1);
    __syncthreads();

    int c = hist[t];
    scanv[t] = c;
    __syncthreads();
    for (int off = 1; off < 256; off <<= 1) {
        int add = (t >= off) ? scanv[t - off] : 0;
        __syncthreads();
        scanv[t] += add;
        __syncthreads();
    }
    int base = scanv[t] - c;  // exclusive
    cur[t] = base;
    __syncthreads();

    for (int i = t; i < n; i += 256) {
        unsigned int r = rec[i];
        int p = atomicAdd(&cur[r >> 24], 1);
        sorted[p] = (int)(r & 0xFFFFFF);
    }
    __syncthreads();

    for (int i = t; i < n; i += 256) csr[(size_t)b * BCAP + i] = sorted[i];

    int v = b * 256 + t;
    if (v < NN) {
        st[v] = b * BCAP + base;
        en[v] = b * BCAP + base + c;
        dis[v] = rsqrtf((float)(c + 1));
    }
}

// ---------------- tiled GEMM core (64 rows, padded-17 float4 LDS) ----------------

__device__ __forceinline__ void gemm_tile_compute(const float4* __restrict__ xs4,
                                                  const float4* __restrict__ ws4,
                                                  int ty, int tx, float acc[4][4]) {
#pragma unroll 2
    for (int k4 = 0; k4 < 16; ++k4) {
        float4 xa0 = xs4[(ty * 4 + 0) * 17 + k4];
        float4 xa1 = xs4[(ty * 4 + 1) * 17 + k4];
        float4 xa2 = xs4[(ty * 4 + 2) * 17 + k4];
        float4 xa3 = xs4[(ty * 4 + 3) * 17 + k4];
        float4 wk0 = ws4[(k4 * 4 + 0) * 16 + tx];
        float4 wk1 = ws4[(k4 * 4 + 1) * 16 + tx];
        float4 wk2 = ws4[(k4 * 4 + 2) * 16 + tx];
        float4 wk3 = ws4[(k4 * 4 + 3) * 16 + tx];
#pragma unroll
        for (int kk = 0; kk < 4; ++kk) {
            float4 wv = (kk == 0) ? wk0 : (kk == 1) ? wk1 : (kk == 2) ? wk2 : wk3;
            float x0 = GETC(xa0, kk), x1 = GETC(xa1, kk);
            float x2 = GETC(xa2, kk), x3 = GETC(xa3, kk);
            acc[0][0] += x0 * wv.x; acc[0][1] += x0 * wv.y; acc[0][2] += x0 * wv.z; acc[0][3] += x0 * wv.w;
            acc[1][0] += x1 * wv.x; acc[1][1] += x1 * wv.y; acc[1][2] += x1 * wv.z; acc[1][3] += x1 * wv.w;
            acc[2][0] += x2 * wv.x; acc[2][1] += x2 * wv.y; acc[2][2] += x2 * wv.z; acc[2][3] += x2 * wv.w;
            acc[3][0] += x3 * wv.x; acc[3][1] += x3 * wv.y; acc[3][2] += x3 * wv.z; acc[3][3] += x3 * wv.w;
        }
    }
}

__global__ __launch_bounds__(256) void gemm64_f32in_kernel(const float* __restrict__ X,
                                                           const float* __restrict__ W,
                                                           const float* __restrict__ dis,
                                                           bf16_t* __restrict__ Hout, int n) {
    __shared__ float4 xs4[64 * 17];   // padded rows
    __shared__ float4 ws4[64 * 16];
    const int tx = threadIdx.x & 15;
    const int ty = threadIdx.x >> 4;
    const int row0 = blockIdx.x * 64;

    const float4* X4 = reinterpret_cast<const float4*>(X + (size_t)row0 * 64);
    const float4* W4 = reinterpret_cast<const float4*>(W);

#pragma unroll
    for (int i = 0; i < 4; ++i) {
        int idx = threadIdx.x + i * 256;       // float4 index, 1024 total
        int r = idx >> 4, c4 = idx & 15;
        int row = row0 + r;
        xs4[r * 17 + c4] = (row < n) ? X4[idx] : make_float4(0.f, 0.f, 0.f, 0.f);
        ws4[idx] = W4[idx];
    }
    __syncthreads();

    float acc[4][4] = {};
    gemm_tile_compute(xs4, ws4, ty, tx, acc);

#pragma unroll
    for (int r = 0; r < 4; ++r) {
        int rw = row0 + ty * 4 + r;
        if (rw < n) {
            float d = dis[rw];
            unsigned int lo = (unsigned int)f2bf(acc[r][0] * d) |
                              ((unsigned int)f2bf(acc[r][1] * d) << 16);
            unsigned int hi = (unsigned int)f2bf(acc[r][2] * d) |
                              ((unsigned int)f2bf(acc[r][3] * d) << 16);
            uint2 u; u.x = lo; u.y = hi;
            *reinterpret_cast<uint2*>(&Hout[(size_t)rw * 64 + tx * 4]) = u;
        }
    }
}

// ---------------- FUSED: agg layer-1 + relu + gemm W2 + dis-scale ----------------

__global__ __launch_bounds__(256) void agg_gemm_kernel(const int* __restrict__ csr,
                                                       const int* __restrict__ st,
                                                       const int* __restrict__ en,
                                                       const float* __restrict__ dis,
                                                       const uint4* __restrict__ Hp8,
                                                       const float* __restrict__ bias,
                                                       const float* __restrict__ W2,
                                                       bf16_t* __restrict__ Hout, int n) {
    __shared__ float4 zs4[32 * 17];   // relu(z1), padded rows
    __shared__ float4 ws4[64 * 16];   // W2
    const int lane = threadIdx.x & 63;
    const int g = lane >> 3;
    const int fl = lane & 7;
    const int v0 = blockIdx.x * 32;
    const int lrow = ((threadIdx.x >> 6) << 3) + g;   // local row 0..31
    int v = v0 + lrow;
    if (v >= n) v = n - 1;

    // cooperative W2 load (independent of gather)
    const float4* W4 = reinterpret_cast<const float4*>(W2);
#pragma unroll
    for (int i = 0; i < 4; ++i) ws4[threadIdx.x + i * 256] = W4[threadIdx.x + i * 256];

    // ---- phase 1: gather ----
    int e = st[v];
    const int e1 = en[v];
    float a0[8] = {}, a1[8] = {}, a2[8] = {}, a3[8] = {};
    acc8(a0, Hp8[(size_t)v * 8 + fl]);   // self loop

    for (; e + 4 <= e1; e += 4) {
        int s0 = csr[e];
        int s1 = csr[e + 1];
        int s2 = csr[e + 2];
        int s3 = csr[e + 3];
        uint4 u0 = Hp8[(size_t)s0 * 8 + fl];
        uint4 u1 = Hp8[(size_t)s1 * 8 + fl];
        uint4 u2 = Hp8[(size_t)s2 * 8 + fl];
        uint4 u3 = Hp8[(size_t)s3 * 8 + fl];
        acc8(a0, u0);
        acc8(a1, u1);
        acc8(a2, u2);
        acc8(a3, u3);
    }
    for (; e < e1; ++e) acc8(a1, Hp8[(size_t)csr[e] * 8 + fl]);

    {
        float d = dis[v];
        float4 bA = reinterpret_cast<const float4*>(bias)[fl * 2];
        float4 bB = reinterpret_cast<const float4*>(bias)[fl * 2 + 1];
        float4 zA, zB;
        zA.x = fmaxf(((a0[0] + a1[0]) + (a2[0] + a3[0])) * d + bA.x, 0.f);
        zA.y = fmaxf(((a0[1] + a1[1]) + (a2[1] + a3[1])) * d + bA.y, 0.f);
        zA.z = fmaxf(((a0[2] + a1[2]) + (a2[2] + a3[2])) * d + bA.z, 0.f);
        zA.w = fmaxf(((a0[3] + a1[3]) + (a2[3] + a3[3])) * d + bA.w, 0.f);
        zB.x = fmaxf(((a0[4] + a1[4]) + (a2[4] + a3[4])) * d + bB.x, 0.f);
        zB.y = fmaxf(((a0[5] + a1[5]) + (a2[5] + a3[5])) * d + bB.y, 0.f);
        zB.z = fmaxf(((a0[6] + a1[6]) + (a2[6] + a3[6])) * d + bB.z, 0.f);
        zB.w = fmaxf(((a0[7] + a1[7]) + (a2[7] + a3[7])) * d + bB.w, 0.f);
        zs4[lrow * 17 + fl * 2]     = zA;
        zs4[lrow * 17 + fl * 2 + 1] = zB;
    }
    __syncthreads();

    // ---- phase 2: 32-row tile gemm, thread owns 2 rows x 4 cols ----
    const int tx = threadIdx.x & 15;
    const int ty = threadIdx.x >> 4;
    float acc[2][4] = {};
#pragma unroll 2
    for (int k4 = 0; k4 < 16; ++k4) {
        float4 xa0 = zs4[(ty * 2 + 0) * 17 + k4];
        float4 xa1 = zs4[(ty * 2 + 1) * 17 + k4];
        float4 wk0 = ws4[(k4 * 4 + 0) * 16 + tx];
        float4 wk1 = ws4[(k4 * 4 + 1) * 16 + tx];
        float4 wk2 = ws4[(k4 * 4 + 2) * 16 + tx];
        float4 wk3 = ws4[(k4 * 4 + 3) * 16 + tx];
#pragma unroll
        for (int kk = 0; kk < 4; ++kk) {
            float4 wv = (kk == 0) ? wk0 : (kk == 1) ? wk1 : (kk == 2) ? wk2 : wk3;
            float x0 = GETC(xa0, kk), x1 = GETC(xa1, kk);
            acc[0][0] += x0 * wv.x; acc[0][1] += x0 * wv.y; acc[0][2] += x0 * wv.z; acc[0][3] += x0 * wv.w;
            acc[1][0] += x1 * wv.x; acc[1][1] += x1 * wv.y; acc[1][2] += x1 * wv.z; acc[1][3] += x1 * wv.w;
        }
    }
#pragma unroll
    for (int r = 0; r < 2; ++r) {
        int rw = v0 + ty * 2 + r;
        if (rw < n) {
            float d = dis[rw];
            unsigned int lo = (unsigned int)f2bf(acc[r][0] * d) |
                              ((unsigned int)f2bf(acc[r][1] * d) << 16);
            unsigned int hi = (unsigned int)f2bf(acc[r][2] * d) |
                              ((unsigned int)f2bf(acc[r][3] * d) << 16);
            uint2 u; u.x = lo; u.y = hi;
            *reinterpret_cast<uint2*>(&Hout[(size_t)rw * 64 + tx * 4]) = u;
        }
    }
}

// ---------------- gather aggregation (layer 2): 8-lane group per node, uint4 lanes ----------------

__global__ __launch_bounds__(256) void agg_kernel(const int* __restrict__ csr,
                                                  const int* __restrict__ st,
                                                  const int* __restrict__ en,
                                                  const float* __restrict__ dis,
                                                  const uint4* __restrict__ Hp8,
                                                  const float* __restrict__ bias,
                                                  uint4* __restrict__ Z8, int n) {
    const int lane = threadIdx.x & 63;
    const int g = lane >> 3;        // group 0..7
    const int fl = lane & 7;        // feature-lane
    int v = blockIdx.x * 32 + ((threadIdx.x >> 6) << 3) + g;
    const bool act = v < n;
    if (!act) v = n - 1;

    int e = st[v];
    const int e1 = en[v];

    float a0[8] = {}, a1[8] = {}, a2[8] = {}, a3[8] = {};
    acc8(a0, Hp8[(size_t)v * 8 + fl]);   // self loop seeds chain 0

    for (; e + 4 <= e1; e += 4) {
        int s0 = csr[e];
        int s1 = csr[e + 1];
        int s2 = csr[e + 2];
        int s3 = csr[e + 3];
        uint4 u0 = Hp8[(size_t)s0 * 8 + fl];
        uint4 u1 = Hp8[(size_t)s1 * 8 + fl];
        uint4 u2 = Hp8[(size_t)s2 * 8 + fl];
        uint4 u3 = Hp8[(size_t)s3 * 8 + fl];
        acc8(a0, u0);
        acc8(a1, u1);
        acc8(a2, u2);
        acc8(a3, u3);
    }
    for (; e < e1; ++e) {
        acc8(a1, Hp8[(size_t)csr[e] * 8 + fl]);
    }

    if (act) {
        float d = dis[v];
        float4 bA = reinterpret_cast<const float4*>(bias)[fl * 2];
        float4 bB = reinterpret_cast<const float4*>(bias)[fl * 2 + 1];
        float z0 = ((a0[0] + a1[0]) + (a2[0] + a3[0])) * d + bA.x;
        float z1 = ((a0[1] + a1[1]) + (a2[1] + a3[1])) * d + bA.y;
        float z2 = ((a0[2] + a1[2]) + (a2[2] + a3[2])) * d + bA.z;
        float z3 = ((a0[3] + a1[3]) + (a2[3] + a3[3])) * d + bA.w;
        float z4 = ((a0[4] + a1[4]) + (a2[4] + a3[4])) * d + bB.x;
        float z5 = ((a0[5] + a1[5]) + (a2[5] + a3[5])) * d + bB.y;
        float z6 = ((a0[6] + a1[6]) + (a2[6] + a3[6])) * d + bB.z;
        float z7 = ((a0[7] + a1[7]) + (a2[7] + a3[7])) * d + bB.w;
        uint4 u;
        u.x = (unsigned int)f2bf(z0) | ((unsigned int)f2bf(z1) << 16);
        u.y = (unsigned int)f2bf(z2) | ((unsigned int)f2bf(z3) << 16);
        u.z = (unsigned int)f2bf(z4) | ((unsigned int)f2bf(z5) << 16);
        u.w = (unsigned int)f2bf(z6) | ((unsigned int)f2bf(z7) << 16);
        Z8[(size_t)v * 8 + fl] = u;
    }
}

// ---------------- decoder: 8-lane group per pair, uint4 lanes ----------------

__global__ __launch_bounds__(256) void decode_kernel(const int* __restrict__ pos,
                                                     const int* __restrict__ neg,
                                                     const uint4* __restrict__ Z8,
                                                     float* __restrict__ out) {
    const int lane = threadIdx.x & 63;
    const int fl = lane & 7;
    const int pair = blockIdx.x * 32 + ((threadIdx.x >> 6) << 3) + (lane >> 3);
    if (pair >= NPOS + NNEG) return;
    int a, b;
    if (pair < NPOS) {
        a = pos[pair];
        b = pos[NPOS + pair];
    } else {
        int p = pair - NPOS;
        a = neg[p];
        b = neg[NNEG + p];
    }
    uint4 ua = Z8[(size_t)a * 8 + fl];
    uint4 ub = Z8[(size_t)b * 8 + fl];
    float v = ulo(ua.x) * ulo(ub.x) + uhi(ua.x) * uhi(ub.x)
            + ulo(ua.y) * ulo(ub.y) + uhi(ua.y) * uhi(ub.y)
            + ulo(ua.z) * ulo(ub.z) + uhi(ua.z) * uhi(ub.z)
            + ulo(ua.w) * ulo(ub.w) + uhi(ua.w) * uhi(ub.w);
#pragma unroll
    for (int off = 4; off > 0; off >>= 1) v += __shfl_xor(v, off, 64);
    if (fl == 0) out[pair] = v;
}

// ---------------- fallback (round-0 atomic path, all f32) ----------------

__global__ __launch_bounds__(256) void init_deg_kernel(float* __restrict__ deg, int n) {
    int i = blockIdx.x * 256 + threadIdx.x;
    if (i < n) deg[i] = 1.0f;
}
__global__ __launch_bounds__(256) void deg_count_kernel(const int* __restrict__ dst,
                                                        float* __restrict__ deg, int e) {
    int i = blockIdx.x * 256 + threadIdx.x;
    if (i < e) atomicAdd(&deg[dst[i]], 1.0f);
}
__global__ __launch_bounds__(256) void dis_kernel(float* __restrict__ deg, int n) {
    int i = blockIdx.x * 256 + threadIdx.x;
    if (i < n) deg[i] = rsqrtf(deg[i]);
}
template <bool RELU>
__global__ __launch_bounds__(256) void gemm64_f32out_kernel(const float* __restrict__ X,
                                                            const float* __restrict__ W,
                                                            float* __restrict__ Hout, int n) {
    __shared__ float xs[64][64];
    const int lane = threadIdx.x & 63;
    const int wid = threadIdx.x >> 6;
    float w[64];
#pragma unroll
    for (int k = 0; k < 64; ++k) w[k] = W[k * 64 + lane];
    const int row0 = blockIdx.x * 64;
#pragma unroll
    for (int i = 0; i < 16; ++i) {
        int idx = threadIdx.x + i * 256;
        int r = idx >> 6, c = idx & 63;
        int row = row0 + r;
        float v = (row < n) ? X[(size_t)row * 64 + c] : 0.0f;
        if (RELU) v = fmaxf(v, 0.0f);
        xs[r][c] = v;
    }
    __syncthreads();
#pragma unroll 1
    for (int rr = 0; rr < 16; ++rr) {
        int r = wid * 16 + rr;
        int row = row0 + r;
        if (row < n) {
            float acc = 0.0f;
#pragma unroll
            for (int k = 0; k < 64; ++k) acc += xs[r][k] * w[k];
            Hout[(size_t)row * 64 + lane] = acc;
        }
    }
}
__global__ __launch_bounds__(256) void selfloop_init_kernel(const float* __restrict__ H,
                                                            const float* __restrict__ dis,
                                                            const float* __restrict__ b,
                                                            float* __restrict__ Z, int n) {
    int i = blockIdx.x * 256 + threadIdx.x;
    if (i < n * 16) {
        int v = i >> 4, c = i & 15;
        float d = dis[v], d2 = d * d;
        float4 h4 = reinterpret_cast<const float4*>(H)[i];
        float4 b4 = reinterpret_cast<const float4*>(b)[c];
        float4 z4;
        z4.x = b4.x + h4.x * d2;
        z4.y = b4.y + h4.y * d2;
        z4.z = b4.z + h4.z * d2;
        z4.w = b4.w + h4.w * d2;
        reinterpret_cast<float4*>(Z)[i] = z4;
    }
}
__global__ __launch_bounds__(256) void edge_agg_kernel(const int* __restrict__ src,
                                                       const int* __restrict__ dst,
                                                       const float* __restrict__ dis,
                                                       const float* __restrict__ H,
                                                       float* __restrict__ Z, int e) {
    const int lane = threadIdx.x & 63;
    const int edge = blockIdx.x * 4 + (threadIdx.x >> 6);
    if (edge < e) {
        int s = src[edge];
        int d = dst[edge];
        float nm = dis[s] * dis[d];
        float v = H[(size_t)s * 64 + lane] * nm;
        atomicAdd(&Z[(size_t)d * 64 + lane], v);
    }
}
__global__ __launch_bounds__(256) void decode_f32_kernel(const int* __restrict__ pos,
                                                         const int* __restrict__ neg,
                                                         const float* __restrict__ Z,
                                                         float* __restrict__ out) {
    const int lane = threadIdx.x & 63;
    const int pair = blockIdx.x * 4 + (threadIdx.x >> 6);
    if (pair >= NPOS + NNEG) return;
    int a, b;
    if (pair < NPOS) {
        a = pos[pair];
        b = pos[NPOS + pair];
    } else {
        int p = pair - NPOS;
        a = neg[p];
        b = neg[NNEG + p];
    }
    float v = Z[(size_t)a * 64 + lane] * Z[(size_t)b * 64 + lane];
#pragma unroll
    for (int off = 32; off > 0; off >>= 1) v += __shfl_down(v, off, 64);
    if (lane == 0) out[pair] = v;
}

// ---------------- launch ----------------

extern "C" void kernel_launch(void* const* d_in, const int* in_sizes, int n_in,
                              void* d_out, int out_size, void* d_ws, size_t ws_size,
                              hipStream_t stream) {
    const float* x   = (const float*)d_in[0];
    const int*   ei  = (const int*)d_in[1];
    const int*   pos = (const int*)d_in[2];
    const int*   neg = (const int*)d_in[3];
    const float* W1  = (const float*)d_in[4];
    const float* b1  = (const float*)d_in[5];
    const float* W2  = (const float*)d_in[6];
    const float* b2  = (const float*)d_in[7];
    float* out = (float*)d_out;

    const int* src = ei;
    const int* dst = ei + NE;

    char* ws = (char*)d_ws;
    size_t o = 0;
    auto alloc = [&](size_t bytes) {
        size_t p = o;
        o = (o + bytes + 255) & ~(size_t)255;
        return p;
    };
    float*        dis  = (float*)(ws + alloc((size_t)NN * 4));
    int*          gcur = (int*)(ws + alloc((size_t)NBUCK * 4));
    unsigned int* brec = (unsigned int*)(ws + alloc((size_t)NBUCK * BCAP * 4));
    int*          csr  = (int*)(ws + alloc((size_t)NBUCK * BCAP * 4));
    int*          stA  = (int*)(ws + alloc((size_t)NN * 4));
    int*          enA  = (int*)(ws + alloc((size_t)NN * 4));
    bf16_t*       bufA = (bf16_t*)(ws + alloc((size_t)NN * 64 * 2));
    bf16_t*       bufB = (bf16_t*)(ws + alloc((size_t)NN * 64 * 2));

    if (o <= ws_size) {
        // ---- bucketed CSR gather path (bf16, fused agg1+gemm2) ----
        zero_gcur_kernel<<<(NBUCK + 255) / 256, 256, 0, stream>>>(gcur);
        bin_kernel<<<(NE + TILE - 1) / TILE, 512, 0, stream>>>(src, dst, gcur, brec);
        bucket_csr_kernel<<<NBUCK, 256, 0, stream>>>(gcur, brec, csr, stA, enA, dis);

        gemm64_f32in_kernel<<<(NN + 63) / 64, 256, 0, stream>>>(x, W1, dis, bufA, NN);

        // fused: agg layer1 (reads bufA) + relu + @W2 + dis -> bufB (= H2')
        agg_gemm_kernel<<<(NN + 31) / 32, 256, 0, stream>>>(csr, stA, enA, dis,
                                                            (const uint4*)bufA, b1, W2,
                                                            bufB, NN);

        // agg layer2 -> bufA (= z2)
        agg_kernel<<<(NN + 31) / 32, 256, 0, stream>>>(csr, stA, enA, dis,
                                                       (const uint4*)bufB, b2,
                                                       (uint4*)bufA, NN);

        decode_kernel<<<((NPOS + NNEG) + 31) / 32, 256, 0, stream>>>(pos, neg,
                                                                     (const uint4*)bufA, out);
    } else {
        // ---- fallback: atomic scatter path (f32) ----
        float* fdis = (float*)ws;
        size_t foff = ((size_t)NN * 4 + 255) / 256 * 256;
        float* fA = (float*)(ws + foff);
        float* fB = fA + (size_t)NN * 64;

        init_deg_kernel<<<(NN + 255) / 256, 256, 0, stream>>>(fdis, NN);
        deg_count_kernel<<<(NE + 255) / 256, 256, 0, stream>>>(dst, fdis, NE);
        dis_kernel<<<(NN + 255) / 256, 256, 0, stream>>>(fdis, NN);

        gemm64_f32out_kernel<false><<<(NN + 63) / 64, 256, 0, stream>>>(x, W1, fA, NN);
        selfloop_init_kernel<<<(NN * 16 + 255) / 256, 256, 0, stream>>>(fA, fdis, b1, fB, NN);
        edge_agg_kernel<<<(NE + 3) / 4, 256, 0, stream>>>(src, dst, fdis, fA, fB, NE);

        gemm64_f32out_kernel<true><<<(NN + 63) / 64, 256, 0, stream>>>(fB, W2, fA, NN);
        selfloop_init_kernel<<<(NN * 16 + 255) / 256, 256, 0, stream>>>(fA, fdis, b2, fB, NN);
        edge_agg_kernel<<<(NE + 3) / 4, 256, 0, stream>>>(src, dst, fdis, fA, fB, NE);

        decode_f32_kernel<<<((NPOS + NNEG) + 3) / 4, 256, 0, stream>>>(pos, neg, fB, out);
    }
}